// Round 4
// baseline (338.068 us; speedup 1.0000x reference)
//
#include <hip/hip_runtime.h>

// HeatMap: out[b,q,t,h,w,f] = relu( sum_g score(b,q,t,h,w,g) * W[g,f] + bias[f] )
// score = dot_c(dec[b,q,t,g,:], enc[b,t,h,w,g,:]); b=4,q=16,t=8,h=w=16,g=8,c=64,f=512.
// Output 268 MB fp32 -> write-BW bound (floor ~43 us at 6.3 TB/s).
//
// Changes vs round 2:
//  - wid order (b,t,h,q) + bijective XCD-chunk swizzle: the 16 q-waves sharing one
//    enc row are now adjacent and on the same XCD -> enc fetched once (16.8 MB),
//    per-XCD enc working set 2 MB (fits 4 MB L2).
//  - two-phase halves: compute 8 scores (loads+shfl reduce) first, then a pure
//    readlane+FMA+store streaming phase -> no global-load latency on store path.
//  - nontemporal stores for out (write-only, 268 MB) to keep enc in L2.

typedef float f32x4 __attribute__((ext_vector_type(4)));

__device__ __forceinline__ float bcast_lane(float v, int srcLane) {
    return __uint_as_float(__builtin_amdgcn_readlane(__float_as_uint(v), srcLane));
}

__global__ __launch_bounds__(256) void heatmap_kernel(
    const float* __restrict__ dec,   // (4,20,8,512)
    const float* __restrict__ enc,   // (4,8,16,16,512)
    const float* __restrict__ W,     // (8,512)
    const float* __restrict__ bias,  // (512,)
    float* __restrict__ out)         // (4,16,8,16,16,512)
{
    const int tid  = threadIdx.x;
    const int lane = tid & 63;

    // XCD-chunk swizzle: 2048 blocks, 8 XCDs, 256 contiguous blocks per XCD.
    const int bid = blockIdx.x;
    const int sw  = (bid & 7) * 256 + (bid >> 3);
    const int wid = sw * 4 + (tid >> 6);          // 0..8191, order (b,t,h,q)

    const int q = wid & 15;
    const int h = (wid >> 4) & 15;
    const int t = (wid >> 8) & 7;
    const int b = wid >> 11;

    const int f0 = lane * 8;   // per-lane f-slice; also per-lane (g,c) slice: g=lane>>3, c=(lane&7)*8

    // Per-lane dec fragment (phase-1 operand). q-dim of btn_dec is 20; use 0..15.
    const float* decp = dec + (size_t)((b * 20 + q) * 8 + t) * 512 + f0;
    const f32x4 d0 = *reinterpret_cast<const f32x4*>(decp);
    const f32x4 d1 = *reinterpret_cast<const f32x4*>(decp + 4);

    // Per-lane W/bias fragments (phase-2 operands; L1-hot, loaded once per wave).
    f32x4 Wr0[8], Wr1[8];
#pragma unroll
    for (int g = 0; g < 8; ++g) {
        Wr0[g] = *reinterpret_cast<const f32x4*>(W + g * 512 + f0);
        Wr1[g] = *reinterpret_cast<const f32x4*>(W + g * 512 + f0 + 4);
    }
    const f32x4 bi0 = *reinterpret_cast<const f32x4*>(bias + f0);
    const f32x4 bi1 = *reinterpret_cast<const f32x4*>(bias + f0 + 4);

    const size_t ebase = (size_t)((b * 8 + t) * 256 + h * 16) * 512 + f0;

    const int owid = ((b * 16 + q) * 8 + t) * 16 + h;   // out row index in (b,q,t,h) order
    float* orow = out + (size_t)owid * (16 * 512) + f0;

#pragma unroll
    for (int half = 0; half < 2; ++half) {
        // ---- Phase 1: scores for 8 w positions (loads + dot + 8-lane xor reduce) ----
        float pw[8];
#pragma unroll
        for (int i = 0; i < 8; ++i) {
            const int w = half * 8 + i;
            const float* ep = enc + ebase + (size_t)w * 512;
            const f32x4 e0 = *reinterpret_cast<const f32x4*>(ep);
            const f32x4 e1 = *reinterpret_cast<const f32x4*>(ep + 4);
            float p = d0.x * e0.x + d0.y * e0.y + d0.z * e0.z + d0.w * e0.w
                    + d1.x * e1.x + d1.y * e1.y + d1.z * e1.z + d1.w * e1.w;
            p += __shfl_xor(p, 1);
            p += __shfl_xor(p, 2);
            p += __shfl_xor(p, 4);
            pw[i] = p;   // lanes g*8.. hold score[g]
        }

        // ---- Phase 2: broadcast scores, project to f, relu, streaming store ----
#pragma unroll
        for (int i = 0; i < 8; ++i) {
            const int w = half * 8 + i;
            float sg[8];
#pragma unroll
            for (int g = 0; g < 8; ++g)
                sg[g] = bcast_lane(pw[i], g * 8);

            f32x4 a0 = bi0, a1 = bi1;
#pragma unroll
            for (int g = 0; g < 8; ++g) {
                a0 += sg[g] * Wr0[g];
                a1 += sg[g] * Wr1[g];
            }
            a0.x = fmaxf(a0.x, 0.f); a0.y = fmaxf(a0.y, 0.f);
            a0.z = fmaxf(a0.z, 0.f); a0.w = fmaxf(a0.w, 0.f);
            a1.x = fmaxf(a1.x, 0.f); a1.y = fmaxf(a1.y, 0.f);
            a1.z = fmaxf(a1.z, 0.f); a1.w = fmaxf(a1.w, 0.f);

            float* op = orow + (size_t)w * 512;
            __builtin_nontemporal_store(a0, reinterpret_cast<f32x4*>(op));
            __builtin_nontemporal_store(a1, reinterpret_cast<f32x4*>(op + 4));
        }
    }
}

extern "C" void kernel_launch(void* const* d_in, const int* in_sizes, int n_in,
                              void* d_out, int out_size, void* d_ws, size_t ws_size,
                              hipStream_t stream) {
    const float* dec  = (const float*)d_in[0];
    const float* enc  = (const float*)d_in[1];
    const float* W    = (const float*)d_in[2];
    const float* bias = (const float*)d_in[3];
    float* out = (float*)d_out;

    // 8192 waves = 4*8*16*16 (b,t,h,q); 4 waves per block, 2048 blocks.
    heatmap_kernel<<<2048, 256, 0, stream>>>(dec, enc, W, bias, out);
}

// Round 6
// 298.561 us; speedup vs baseline: 1.1323x; 1.1323x over previous
//
#include <hip/hip_runtime.h>

// HeatMap: out[b,q,t,h,w,f] = relu( sum_g score(b,q,t,h,w,g) * W[g,f] + bias[f] )
// score = dot_c(dec[b,q,t,g,:], enc[b,t,h,w,g,:]); b=4,q=16,t=8,h=w=16,g=8,c=64,f=512.
// Output 268 MB fp32 -> write-BW bound (floor ~43 us at 6.3 TB/s achievable).
//
// Round 5: back to round-2 single-phase loop + NORMAL stores (nontemporal stores and
// the two-phase split regressed dur 299.5 -> 338 in round 4; enc fits L3 so the
// over-fetch theory was wrong). Kept: (b,t,h,q) wid order + bijective XCD swizzle
// (cheap, possibly small L2 win).

typedef float f32x4 __attribute__((ext_vector_type(4)));

__device__ __forceinline__ float bcast_lane(float v, int srcLane) {
    return __uint_as_float(__builtin_amdgcn_readlane(__float_as_uint(v), srcLane));
}

__global__ __launch_bounds__(256) void heatmap_kernel(
    const float* __restrict__ dec,   // (4,20,8,512)
    const float* __restrict__ enc,   // (4,8,16,16,512)
    const float* __restrict__ W,     // (8,512)
    const float* __restrict__ bias,  // (512,)
    float* __restrict__ out)         // (4,16,8,16,16,512)
{
    const int tid  = threadIdx.x;
    const int lane = tid & 63;

    // XCD-chunk swizzle: 2048 blocks, 8 XCDs, 256 contiguous blocks per XCD.
    const int bid = blockIdx.x;
    const int sw  = (bid & 7) * 256 + (bid >> 3);
    const int wid = sw * 4 + (tid >> 6);          // 0..8191, order (b,t,h,q)

    const int q = wid & 15;
    const int h = (wid >> 4) & 15;
    const int t = (wid >> 8) & 7;
    const int b = wid >> 11;

    const int f0 = lane * 8;   // per-lane f-slice; also per-lane (g,c) slice: g=lane>>3, c=(lane&7)*8

    // Per-lane W fragment (64 VGPRs) + bias, loaded once per wave (L1-hot).
    f32x4 Wr0[8], Wr1[8];
#pragma unroll
    for (int g = 0; g < 8; ++g) {
        Wr0[g] = *reinterpret_cast<const f32x4*>(W + g * 512 + f0);
        Wr1[g] = *reinterpret_cast<const f32x4*>(W + g * 512 + f0 + 4);
    }
    const f32x4 bi0 = *reinterpret_cast<const f32x4*>(bias + f0);
    const f32x4 bi1 = *reinterpret_cast<const f32x4*>(bias + f0 + 4);

    // Per-lane dec fragment, fixed per wave. q-dim of btn_dec is 20; use 0..15.
    const float* decp = dec + (size_t)((b * 20 + q) * 8 + t) * 512 + f0;
    const f32x4 d0 = *reinterpret_cast<const f32x4*>(decp);
    const f32x4 d1 = *reinterpret_cast<const f32x4*>(decp + 4);

    const size_t ebase = (size_t)((b * 8 + t) * 256 + h * 16) * 512 + f0;

    const int owid = ((b * 16 + q) * 8 + t) * 16 + h;   // out row index in (b,q,t,h) order
    float* orow = out + (size_t)owid * (16 * 512) + f0;

#pragma unroll 4
    for (int w = 0; w < 16; ++w) {
        const float* ep = enc + ebase + (size_t)w * 512;
        const f32x4 e0 = *reinterpret_cast<const f32x4*>(ep);
        const f32x4 e1 = *reinterpret_cast<const f32x4*>(ep + 4);

        // Per-lane partial of score[g = lane>>3] over its 8 c's.
        float p = d0.x * e0.x + d0.y * e0.y + d0.z * e0.z + d0.w * e0.w
                + d1.x * e1.x + d1.y * e1.y + d1.z * e1.z + d1.w * e1.w;

        // Reduce within each 8-lane group (DPP, no LDS).
        p += __shfl_xor(p, 1);
        p += __shfl_xor(p, 2);
        p += __shfl_xor(p, 4);

        // Broadcast the 8 scores to all lanes as SGPRs.
        float sg[8];
#pragma unroll
        for (int g = 0; g < 8; ++g)
            sg[g] = bcast_lane(p, g * 8);

        // Project to f-space, relu, coalesced store.
        f32x4 a0 = bi0, a1 = bi1;
#pragma unroll
        for (int g = 0; g < 8; ++g) {
            a0 += sg[g] * Wr0[g];
            a1 += sg[g] * Wr1[g];
        }
        a0.x = fmaxf(a0.x, 0.f); a0.y = fmaxf(a0.y, 0.f);
        a0.z = fmaxf(a0.z, 0.f); a0.w = fmaxf(a0.w, 0.f);
        a1.x = fmaxf(a1.x, 0.f); a1.y = fmaxf(a1.y, 0.f);
        a1.z = fmaxf(a1.z, 0.f); a1.w = fmaxf(a1.w, 0.f);

        float* op = orow + (size_t)w * 512;
        *reinterpret_cast<f32x4*>(op)     = a0;
        *reinterpret_cast<f32x4*>(op + 4) = a1;
    }
}

extern "C" void kernel_launch(void* const* d_in, const int* in_sizes, int n_in,
                              void* d_out, int out_size, void* d_ws, size_t ws_size,
                              hipStream_t stream) {
    const float* dec  = (const float*)d_in[0];
    const float* enc  = (const float*)d_in[1];
    const float* W    = (const float*)d_in[2];
    const float* bias = (const float*)d_in[3];
    float* out = (float*)d_out;

    // 8192 waves = 4*8*16*16 (b,t,h,q); 4 waves per block, 2048 blocks.
    heatmap_kernel<<<2048, 256, 0, stream>>>(dec, enc, W, bias, out);
}

// Round 8
// 292.040 us; speedup vs baseline: 1.1576x; 1.0223x over previous
//
#include <hip/hip_runtime.h>

// HeatMap: out[b,q,t,h,w,f] = relu( sum_g score(b,q,t,h,w,g) * W[g,f] + bias[f] )
// score = dot_c(dec[b,q,t,g,:], enc[b,t,h,w,g,:]); b=4,q=16,t=8,h=w=16,g=8,c=64,f=512.
// Output 268 MB fp32 -> write-BW bound (floor ~45 us incl. reads at 6.3 TB/s).
//
// Round 7 (one variable vs round 5/6): store f-slice made CONTIGUOUS per instruction.
// Old: f0=lane*8, stores at f0/f0+4 -> each global_store_dwordx4 wrote 16 B at 32-B
// stride, so no instruction fully covered a 64-B line -> TCC read-for-ownership
// fetched the whole 268 MB output from HBM before writing (kernel traffic ~536 MB,
// matches measured 78 us). Fill kernels (contiguous 16 B/lane) show FETCH_SIZE~=0:
// full-line stores skip the fetch. New: store slices fA=lane*4 (f<256) and
// fB=256+lane*4 -> 64 lanes x 16 B contiguous = 16 full lines per store.
// Load slice stays lane*8 (g=lane>>3, c=(lane&7)*8); score math unchanged.

typedef float f32x4 __attribute__((ext_vector_type(4)));

__device__ __forceinline__ float bcast_lane(float v, int srcLane) {
    return __uint_as_float(__builtin_amdgcn_readlane(__float_as_uint(v), srcLane));
}

__global__ __launch_bounds__(256) void heatmap_kernel(
    const float* __restrict__ dec,   // (4,20,8,512)
    const float* __restrict__ enc,   // (4,8,16,16,512)
    const float* __restrict__ W,     // (8,512)
    const float* __restrict__ bias,  // (512,)
    float* __restrict__ out)         // (4,16,8,16,16,512)
{
    const int tid  = threadIdx.x;
    const int lane = tid & 63;

    // XCD-chunk swizzle: 2048 blocks, 8 XCDs, 256 contiguous blocks per XCD.
    const int bid = blockIdx.x;
    const int sw  = (bid & 7) * 256 + (bid >> 3);
    const int wid = sw * 4 + (tid >> 6);          // 0..8191, order (b,t,h,q)

    const int q = wid & 15;
    const int h = (wid >> 4) & 15;
    const int t = (wid >> 8) & 7;
    const int b = wid >> 11;

    const int f0L = lane * 8;        // load slice: g=lane>>3, c=(lane&7)*8
    const int fA  = lane * 4;        // store slice A: f in [0,256), contiguous across lanes
    const int fB  = 256 + lane * 4;  // store slice B: f in [256,512), contiguous

    // Per-lane W fragment (64 VGPRs) + bias for the STORE slices, loaded once (L1-hot).
    f32x4 Wr0[8], Wr1[8];
#pragma unroll
    for (int g = 0; g < 8; ++g) {
        Wr0[g] = *reinterpret_cast<const f32x4*>(W + g * 512 + fA);
        Wr1[g] = *reinterpret_cast<const f32x4*>(W + g * 512 + fB);
    }
    const f32x4 bi0 = *reinterpret_cast<const f32x4*>(bias + fA);
    const f32x4 bi1 = *reinterpret_cast<const f32x4*>(bias + fB);

    // Per-lane dec fragment, fixed per wave. q-dim of btn_dec is 20; use 0..15.
    const float* decp = dec + (size_t)((b * 20 + q) * 8 + t) * 512 + f0L;
    const f32x4 d0 = *reinterpret_cast<const f32x4*>(decp);
    const f32x4 d1 = *reinterpret_cast<const f32x4*>(decp + 4);

    const size_t ebase = (size_t)((b * 8 + t) * 256 + h * 16) * 512 + f0L;

    const int owid = ((b * 16 + q) * 8 + t) * 16 + h;   // out row index in (b,q,t,h) order
    float* orowA = out + (size_t)owid * (16 * 512) + fA;
    float* orowB = out + (size_t)owid * (16 * 512) + fB;

#pragma unroll 4
    for (int w = 0; w < 16; ++w) {
        const float* ep = enc + ebase + (size_t)w * 512;
        const f32x4 e0 = *reinterpret_cast<const f32x4*>(ep);
        const f32x4 e1 = *reinterpret_cast<const f32x4*>(ep + 4);

        // Per-lane partial of score[g = lane>>3] over its 8 c's.
        float p = d0.x * e0.x + d0.y * e0.y + d0.z * e0.z + d0.w * e0.w
                + d1.x * e1.x + d1.y * e1.y + d1.z * e1.z + d1.w * e1.w;

        // Reduce within each 8-lane group (DPP, no LDS).
        p += __shfl_xor(p, 1);
        p += __shfl_xor(p, 2);
        p += __shfl_xor(p, 4);

        // Broadcast the 8 scores to all lanes as SGPRs.
        float sg[8];
#pragma unroll
        for (int g = 0; g < 8; ++g)
            sg[g] = bcast_lane(p, g * 8);

        // Project to f-space, relu, full-line coalesced stores.
        f32x4 a0 = bi0, a1 = bi1;
#pragma unroll
        for (int g = 0; g < 8; ++g) {
            a0 += sg[g] * Wr0[g];
            a1 += sg[g] * Wr1[g];
        }
        a0.x = fmaxf(a0.x, 0.f); a0.y = fmaxf(a0.y, 0.f);
        a0.z = fmaxf(a0.z, 0.f); a0.w = fmaxf(a0.w, 0.f);
        a1.x = fmaxf(a1.x, 0.f); a1.y = fmaxf(a1.y, 0.f);
        a1.z = fmaxf(a1.z, 0.f); a1.w = fmaxf(a1.w, 0.f);

        *reinterpret_cast<f32x4*>(orowA + (size_t)w * 512) = a0;
        *reinterpret_cast<f32x4*>(orowB + (size_t)w * 512) = a1;
    }
}

extern "C" void kernel_launch(void* const* d_in, const int* in_sizes, int n_in,
                              void* d_out, int out_size, void* d_ws, size_t ws_size,
                              hipStream_t stream) {
    const float* dec  = (const float*)d_in[0];
    const float* enc  = (const float*)d_in[1];
    const float* W    = (const float*)d_in[2];
    const float* bias = (const float*)d_in[3];
    float* out = (float*)d_out;

    // 8192 waves = 4*8*16*16 (b,t,h,q); 4 waves per block, 2048 blocks.
    heatmap_kernel<<<2048, 256, 0, stream>>>(dec, enc, W, bias, out);
}